// Round 1
// baseline (346.935 us; speedup 1.0000x reference)
//
#include <hip/hip_runtime.h>

#define T_TOK   32768
#define B_SEG   8
#define H_HEADS 8
#define D_DIM   128
#define TOK_F   (H_HEADS * D_DIM)   // 1024 floats per token
#define CHUNK   32                  // tokens per block

// ---------------------------------------------------------------------------
// Kernel 1: segment sum over tokens+heads -> sums[B_SEG][D_DIM]
// Block handles CHUNK contiguous tokens; each thread reads one float4/token
// (256 thr * 16 B = 4 KB = one token, fully coalesced). Register accumulate;
// flush via LDS h-reduction + atomicAdd at (rare) segment boundaries.
// ---------------------------------------------------------------------------
__global__ __launch_bounds__(256) void segsum_kernel(
        const float* __restrict__ x, const int* __restrict__ cu,
        float* __restrict__ sums) {
    const int tid = threadIdx.x;
    const int t0  = blockIdx.x * CHUNK;

    int cuv[B_SEG + 1];
#pragma unroll
    for (int i = 0; i <= B_SEG; ++i) cuv[i] = cu[i];

    auto segid = [&](int t) {
        int s = 0;
#pragma unroll
        for (int i = 1; i <= B_SEG; ++i)
            if (cuv[i] <= t) s = i;
        return s;  // searchsorted(cu, t, 'right') - 1
    };

    int cur_seg  = segid(t0);
    int next_cut = cuv[cur_seg + 1];   // guaranteed > t0

    float4 acc = make_float4(0.f, 0.f, 0.f, 0.f);
    __shared__ float smem[TOK_F];
    const float4* x4 = (const float4*)x;

    auto flush = [&](int seg) {  // block-uniform call sites only
        smem[tid * 4 + 0] = acc.x;
        smem[tid * 4 + 1] = acc.y;
        smem[tid * 4 + 2] = acc.z;
        smem[tid * 4 + 3] = acc.w;
        __syncthreads();
        if (tid < D_DIM) {
            float s = 0.f;
#pragma unroll
            for (int h = 0; h < H_HEADS; ++h) s += smem[h * D_DIM + tid];
            atomicAdd(&sums[seg * D_DIM + tid], s);
        }
        __syncthreads();
        acc = make_float4(0.f, 0.f, 0.f, 0.f);
    };

    for (int i = 0; i < CHUNK; ++i) {
        const int t = t0 + i;
        if (t == next_cut) {           // uniform across block
            flush(cur_seg);
            cur_seg  = segid(t);       // skips empty segments correctly
            next_cut = cuv[cur_seg + 1];
        }
        float4 v = x4[(size_t)t * (TOK_F / 4) + tid];
        acc.x += v.x; acc.y += v.y; acc.z += v.z; acc.w += v.w;
    }
    flush(cur_seg);
}

// ---------------------------------------------------------------------------
// Kernel 2: layer 1 fused with pooled-mean normalization.
// h1[b][o] = silu( sum_k (sums[b][k]/(max(cnt,1)*H)) * w1[k][o] + b1[o] )
// ---------------------------------------------------------------------------
__global__ __launch_bounds__(256) void layer1_kernel(
        const float* __restrict__ sums, const int* __restrict__ cu,
        const float* __restrict__ w1, const float* __restrict__ b1,
        float* __restrict__ h1) {
    const int idx = blockIdx.x * 256 + threadIdx.x;  // 8192 = 8 * 1024
    const int b = idx >> 10;
    const int o = idx & 1023;
    const int cnt = cu[b + 1] - cu[b];
    const float scale = 1.0f / (fmaxf((float)cnt, 1.0f) * (float)H_HEADS);
    float acc = b1[o];
#pragma unroll 8
    for (int k = 0; k < D_DIM; ++k)
        acc += (sums[b * D_DIM + k] * scale) * w1[k * 1024 + o];
    h1[idx] = acc / (1.0f + __expf(-acc));  // silu
}

// ---------------------------------------------------------------------------
// Generic B_SEG-row linear layer: out[b][o] = (act?) in[b][:]@w[:,o] + bias[o]
// One thread per output element; consecutive threads hit consecutive w cols
// (coalesced). K, N compile-time -> shifts for /N, %N.
// ---------------------------------------------------------------------------
template <int K, int N, bool ACT>
__global__ __launch_bounds__(256) void linear_kernel(
        const float* __restrict__ in, const float* __restrict__ w,
        const float* __restrict__ bias, float* __restrict__ out) {
    const int idx = blockIdx.x * 256 + threadIdx.x;  // B_SEG * N threads
    const int b = idx / N;
    const int o = idx % N;
    float acc = bias[o];
#pragma unroll 8
    for (int k = 0; k < K; ++k)
        acc += in[b * K + k] * w[k * N + o];
    if (ACT) acc = acc / (1.0f + __expf(-acc));
    out[idx] = acc;
}

// ---------------------------------------------------------------------------
// Final: logits = h2b @ w5 + b5 ; z = (logit1 > logit0); broadcast over H.
// ---------------------------------------------------------------------------
__global__ __launch_bounds__(64) void final_kernel(
        const float* __restrict__ h2b, const float* __restrict__ w5,
        const float* __restrict__ b5, float* __restrict__ out) {
    __shared__ float logits[B_SEG * 2];
    const int tid = threadIdx.x;
    if (tid < B_SEG * 2) {
        const int b = tid >> 1;
        const int j = tid & 1;
        float acc = b5[j];
#pragma unroll 8
        for (int k = 0; k < D_DIM; ++k)
            acc += h2b[b * D_DIM + k] * w5[k * 2 + j];
        logits[tid] = acc;
    }
    __syncthreads();
    if (tid < B_SEG * H_HEADS) {
        const int b = tid >> 3;  // /H_HEADS
        out[tid] = (logits[b * 2 + 1] > logits[b * 2 + 0]) ? 1.0f : 0.0f;
    }
}

extern "C" void kernel_launch(void* const* d_in, const int* in_sizes, int n_in,
                              void* d_out, int out_size, void* d_ws, size_t ws_size,
                              hipStream_t stream) {
    const float* x  = (const float*)d_in[0];
    const int*   cu = (const int*)d_in[1];
    const float* w1 = (const float*)d_in[2];
    const float* b1 = (const float*)d_in[3];
    const float* w2 = (const float*)d_in[4];
    const float* b2 = (const float*)d_in[5];
    const float* w3 = (const float*)d_in[6];
    const float* b3 = (const float*)d_in[7];
    const float* w4 = (const float*)d_in[8];
    const float* b4 = (const float*)d_in[9];
    const float* w5 = (const float*)d_in[10];
    const float* b5 = (const float*)d_in[11];
    float* out = (float*)d_out;

    float* ws   = (float*)d_ws;
    float* sums = ws;                       // 1024
    float* h1   = sums + B_SEG * D_DIM;     // 8192
    float* hm   = h1 + 8192;                // 2048
    float* h2a  = hm + 2048;                // 4096
    float* h2b  = h2a + 4096;               // 1024

    // ws is re-poisoned to 0xAA before every timed launch: zero the accumulator.
    hipMemsetAsync(sums, 0, B_SEG * D_DIM * sizeof(float), stream);

    segsum_kernel<<<T_TOK / CHUNK, 256, 0, stream>>>(x, cu, sums);
    layer1_kernel<<<8 * 1024 / 256, 256, 0, stream>>>(sums, cu, w1, b1, h1);
    linear_kernel<1024, 256, false><<<8 * 256 / 256, 256, 0, stream>>>(h1, w2, b2, hm);
    linear_kernel<256, 512, true><<<8 * 512 / 256, 256, 0, stream>>>(hm, w3, b3, h2a);
    linear_kernel<512, 128, true><<<8 * 128 / 256, 256, 0, stream>>>(h2a, w4, b4, h2b);
    final_kernel<<<1, 64, 0, stream>>>(h2b, w5, b5, out);
}

// Round 2
// 288.533 us; speedup vs baseline: 1.2024x; 1.2024x over previous
//
#include <hip/hip_runtime.h>

#define T_TOK   32768
#define B_SEG   8
#define H_HEADS 8
#define D_DIM   128
#define TOK_F   (H_HEADS * D_DIM)   // 1024 floats per token
#define CHUNK   32                  // tokens per block

// ---------------------------------------------------------------------------
// Kernel 1: segment sum over tokens+heads -> sums[B_SEG][D_DIM]
// 1024 blocks x 32 tokens; each thread reads one float4/token (fully
// coalesced 4 KB/token). Register accumulate; flush via LDS h-reduction +
// atomicAdd at (rare, block-uniform) segment boundaries. HBM-roofline bound:
// 134 MB read => ~20 us floor.
// ---------------------------------------------------------------------------
__global__ __launch_bounds__(256) void segsum_kernel(
        const float* __restrict__ x, const int* __restrict__ cu,
        float* __restrict__ sums) {
    const int tid = threadIdx.x;
    const int t0  = blockIdx.x * CHUNK;

    int cuv[B_SEG + 1];
#pragma unroll
    for (int i = 0; i <= B_SEG; ++i) cuv[i] = cu[i];

    auto segid = [&](int t) {
        int s = 0;
#pragma unroll
        for (int i = 1; i <= B_SEG; ++i)
            if (cuv[i] <= t) s = i;
        return s;  // searchsorted(cu, t, 'right') - 1
    };

    int cur_seg  = segid(t0);
    int next_cut = cuv[cur_seg + 1];   // guaranteed > t0

    float4 acc = make_float4(0.f, 0.f, 0.f, 0.f);
    __shared__ float smem[TOK_F];
    const float4* x4 = (const float4*)x;

    auto flush = [&](int seg) {  // block-uniform call sites only
        smem[tid * 4 + 0] = acc.x;
        smem[tid * 4 + 1] = acc.y;
        smem[tid * 4 + 2] = acc.z;
        smem[tid * 4 + 3] = acc.w;
        __syncthreads();
        if (tid < D_DIM) {
            float s = 0.f;
#pragma unroll
            for (int h = 0; h < H_HEADS; ++h) s += smem[h * D_DIM + tid];
            atomicAdd(&sums[seg * D_DIM + tid], s);
        }
        __syncthreads();
        acc = make_float4(0.f, 0.f, 0.f, 0.f);
    };

    for (int i = 0; i < CHUNK; ++i) {
        const int t = t0 + i;
        if (t == next_cut) {           // uniform across block
            flush(cur_seg);
            cur_seg  = segid(t);       // skips empty segments correctly
            next_cut = cuv[cur_seg + 1];
        }
        float4 v = x4[(size_t)t * (TOK_F / 4) + tid];
        acc.x += v.x; acc.y += v.y; acc.z += v.z; acc.w += v.w;
    }
    flush(cur_seg);
}

// ---------------------------------------------------------------------------
// Split-K linear layer. grid = (N/COLS, B_SEG), block = 256 threads =
// (256/COLS) K-strips x COLS cols. Each thread partial-dots its K-strip,
// LDS reduce, strip 0 adds bias (+silu) and writes. Spreads weight-column
// fetch across B*N/COLS CUs instead of B.
// FUSE_SCALE: multiply input row by pooled-mean scale (layer 1).
// ---------------------------------------------------------------------------
template <int K, int N, int COLS, bool ACT, bool FUSE_SCALE>
__global__ __launch_bounds__(256) void linear2_kernel(
        const float* __restrict__ in, const int* __restrict__ cu,
        const float* __restrict__ w, const float* __restrict__ bias,
        float* __restrict__ out) {
    constexpr int STRIPS = 256 / COLS;
    constexpr int KS     = K / STRIPS;
    const int tid   = threadIdx.x;
    const int col   = tid % COLS;
    const int strip = tid / COLS;
    const int b     = blockIdx.y;
    const int o     = blockIdx.x * COLS + col;

    const float* inb = in + b * K;
    float acc = 0.f;
#pragma unroll 4
    for (int k = strip * KS; k < (strip + 1) * KS; ++k)
        acc += inb[k] * w[(size_t)k * N + o];

    __shared__ float lds[256];
    lds[tid] = acc;
    __syncthreads();
    if (strip == 0) {
        float s = 0.f;
#pragma unroll
        for (int j = 0; j < STRIPS; ++j) s += lds[col + j * COLS];
        if (FUSE_SCALE) {
            const int cnt = cu[b + 1] - cu[b];
            s *= 1.0f / (fmaxf((float)cnt, 1.0f) * (float)H_HEADS);
        }
        s += bias[o];
        if (ACT) s = s / (1.0f + __expf(-s));
        out[b * N + o] = s;
    }
}

// ---------------------------------------------------------------------------
// Layer 4 (512->128, silu) fused with layer 5 (128->2) + argmax-compare +
// broadcast over heads. One block per segment b; 256 thr = 2 K-strips x 128.
// ---------------------------------------------------------------------------
__global__ __launch_bounds__(256) void layer4_final_kernel(
        const float* __restrict__ h2a,   // [B][512]
        const float* __restrict__ w4, const float* __restrict__ b4,
        const float* __restrict__ w5, const float* __restrict__ b5,
        float* __restrict__ out) {
    const int tid   = threadIdx.x;
    const int b     = blockIdx.x;
    const int col   = tid & 127;
    const int strip = tid >> 7;          // 0..1

    const float* inb = h2a + b * 512;
    float acc = 0.f;
#pragma unroll 4
    for (int k = strip * 256; k < strip * 256 + 256; ++k)
        acc += inb[k] * w4[k * 128 + col];

    __shared__ float lds[256];
    __shared__ float h2b[128];
    __shared__ float logits[2];
    lds[tid] = acc;
    __syncthreads();
    if (strip == 0) {
        float s = b4[col] + lds[col] + lds[col + 128];
        h2b[col] = s / (1.0f + __expf(-s));   // silu
    }
    __syncthreads();
    if (tid < 2) {
        float a2 = b5[tid];
#pragma unroll 8
        for (int k = 0; k < 128; ++k) a2 += h2b[k] * w5[k * 2 + tid];
        logits[tid] = a2;
    }
    __syncthreads();
    if (tid < H_HEADS)
        out[b * H_HEADS + tid] = (logits[1] > logits[0]) ? 1.0f : 0.0f;
}

extern "C" void kernel_launch(void* const* d_in, const int* in_sizes, int n_in,
                              void* d_out, int out_size, void* d_ws, size_t ws_size,
                              hipStream_t stream) {
    const float* x  = (const float*)d_in[0];
    const int*   cu = (const int*)d_in[1];
    const float* w1 = (const float*)d_in[2];
    const float* b1 = (const float*)d_in[3];
    const float* w2 = (const float*)d_in[4];
    const float* b2 = (const float*)d_in[5];
    const float* w3 = (const float*)d_in[6];
    const float* b3 = (const float*)d_in[7];
    const float* w4 = (const float*)d_in[8];
    const float* b4 = (const float*)d_in[9];
    const float* w5 = (const float*)d_in[10];
    const float* b5 = (const float*)d_in[11];
    float* out = (float*)d_out;

    float* ws   = (float*)d_ws;
    float* sums = ws;                       // 1024
    float* h1   = sums + B_SEG * D_DIM;     // 8192
    float* hm   = h1 + 8192;                // 2048
    float* h2a  = hm + 2048;                // 4096

    // ws is re-poisoned to 0xAA before every timed launch: zero the accumulator.
    hipMemsetAsync(sums, 0, B_SEG * D_DIM * sizeof(float), stream);

    segsum_kernel<<<T_TOK / CHUNK, 256, 0, stream>>>(x, cu, sums);
    // layer1: 128 -> 1024, silu, pooled-mean scale. grid (16,8) = 128 blocks.
    linear2_kernel<128, 1024, 64, true, true>
        <<<dim3(1024 / 64, B_SEG), 256, 0, stream>>>(sums, cu, w1, b1, h1);
    // layer2: 1024 -> 256, no act. grid (4,8) = 32 blocks (was 8).
    linear2_kernel<1024, 256, 64, false, false>
        <<<dim3(256 / 64, B_SEG), 256, 0, stream>>>(h1, cu, w2, b2, hm);
    // layer3: 256 -> 512, silu. grid (8,8) = 64 blocks.
    linear2_kernel<256, 512, 64, true, false>
        <<<dim3(512 / 64, B_SEG), 256, 0, stream>>>(hm, cu, w3, b3, h2a);
    // layer4 + layer5 + compare + broadcast: 8 blocks.
    layer4_final_kernel<<<B_SEG, 256, 0, stream>>>(h2a, w4, b4, w5, b5, out);
}

// Round 4
// 273.560 us; speedup vs baseline: 1.2682x; 1.0547x over previous
//
#include <hip/hip_runtime.h>

#define T_TOK   32768
#define B_SEG   8
#define H_HEADS 8
#define D_DIM   128
#define TOK_F   (H_HEADS * D_DIM)   // 1024 floats per token
#define CHUNK   32                  // tokens per block

typedef float floatx4 __attribute__((ext_vector_type(4)));  // native vec for nontemporal builtin

// ---------------------------------------------------------------------------
// Kernel 1: segment sum over tokens+heads -> sums[B_SEG][D_DIM]
// 1024 blocks x 32 tokens; each thread reads one float4/token (fully
// coalesced 4 KB/token). Boundary-free blocks (1017/1024) take a statically
// unrolled branch-free loop so the compiler pipelines all 32 dwordx4 loads;
// boundary blocks take the per-token path. HBM-roofline: 134 MB => ~20 us.
// ---------------------------------------------------------------------------
__global__ __launch_bounds__(256) void segsum_kernel(
        const float* __restrict__ x, const int* __restrict__ cu,
        float* __restrict__ sums) {
    const int tid   = threadIdx.x;
    const int t0    = blockIdx.x * CHUNK;
    const int t_end = t0 + CHUNK;

    int cuv[B_SEG + 1];
#pragma unroll
    for (int i = 0; i <= B_SEG; ++i) cuv[i] = cu[i];

    auto segid = [&](int t) {
        int s = 0;
#pragma unroll
        for (int i = 1; i <= B_SEG; ++i)
            if (cuv[i] <= t) s = i;
        return s;  // searchsorted(cu, t, 'right') - 1
    };

    int cur_seg  = segid(t0);
    int next_cut = cuv[cur_seg + 1];   // guaranteed > t0

    floatx4 acc = (floatx4)0.f;
    __shared__ float smem[TOK_F];
    const floatx4* x4 = (const floatx4*)x + tid;

    auto flush = [&](int seg) {  // block-uniform call sites only
        smem[tid * 4 + 0] = acc.x;
        smem[tid * 4 + 1] = acc.y;
        smem[tid * 4 + 2] = acc.z;
        smem[tid * 4 + 3] = acc.w;
        __syncthreads();
        if (tid < D_DIM) {
            float s = 0.f;
#pragma unroll
            for (int h = 0; h < H_HEADS; ++h) s += smem[h * D_DIM + tid];
            atomicAdd(&sums[seg * D_DIM + tid], s);
        }
        __syncthreads();
        acc = (floatx4)0.f;
    };

    if (next_cut >= t_end) {
        // Fast path: whole chunk in one segment. Branch-free, statically
        // unrolled -> deep vmcnt pipelining.
#pragma unroll
        for (int i = 0; i < CHUNK; ++i) {
            floatx4 v = __builtin_nontemporal_load(
                x4 + (size_t)(t0 + i) * (TOK_F / 4));
            acc += v;
        }
        flush(cur_seg);
    } else {
        // Slow path: chunk contains >=1 segment boundary (<=7 blocks total).
        for (int t = t0; t < t_end; ++t) {
            if (t == next_cut) {           // uniform across block
                flush(cur_seg);
                cur_seg  = segid(t);       // skips empty segments correctly
                next_cut = cuv[cur_seg + 1];
            }
            floatx4 v = x4[(size_t)t * (TOK_F / 4)];
            acc += v;
        }
        flush(cur_seg);
    }
}

// ---------------------------------------------------------------------------
// Split-K linear layer. grid = (N/COLS, B_SEG), block = 256 threads =
// (256/COLS) K-strips x COLS cols. Each thread partial-dots its K-strip,
// LDS reduce, strip 0 adds bias (+silu) and writes. Spreads weight-column
// fetch across B*N/COLS CUs.
// FUSE_SCALE: multiply input row by pooled-mean scale (layer 1).
// ---------------------------------------------------------------------------
template <int K, int N, int COLS, bool ACT, bool FUSE_SCALE>
__global__ __launch_bounds__(256) void linear2_kernel(
        const float* __restrict__ in, const int* __restrict__ cu,
        const float* __restrict__ w, const float* __restrict__ bias,
        float* __restrict__ out) {
    constexpr int STRIPS = 256 / COLS;
    constexpr int KS     = K / STRIPS;
    const int tid   = threadIdx.x;
    const int col   = tid % COLS;
    const int strip = tid / COLS;
    const int b     = blockIdx.y;
    const int o     = blockIdx.x * COLS + col;

    const float* inb = in + b * K;
    float acc = 0.f;
#pragma unroll 4
    for (int k = strip * KS; k < (strip + 1) * KS; ++k)
        acc += inb[k] * w[(size_t)k * N + o];

    __shared__ float lds[256];
    lds[tid] = acc;
    __syncthreads();
    if (strip == 0) {
        float s = 0.f;
#pragma unroll
        for (int j = 0; j < STRIPS; ++j) s += lds[col + j * COLS];
        if (FUSE_SCALE) {
            const int cnt = cu[b + 1] - cu[b];
            s *= 1.0f / (fmaxf((float)cnt, 1.0f) * (float)H_HEADS);
        }
        s += bias[o];
        if (ACT) s = s / (1.0f + __expf(-s));
        out[b * N + o] = s;
    }
}

// ---------------------------------------------------------------------------
// Layer 4 (512->128, silu) fused with layer 5 (128->2) + argmax-compare +
// broadcast over heads. One block per segment b; 256 thr = 2 K-strips x 128.
// ---------------------------------------------------------------------------
__global__ __launch_bounds__(256) void layer4_final_kernel(
        const float* __restrict__ h2a,   // [B][512]
        const float* __restrict__ w4, const float* __restrict__ b4,
        const float* __restrict__ w5, const float* __restrict__ b5,
        float* __restrict__ out) {
    const int tid   = threadIdx.x;
    const int b     = blockIdx.x;
    const int col   = tid & 127;
    const int strip = tid >> 7;          // 0..1

    const float* inb = h2a + b * 512;
    float acc = 0.f;
#pragma unroll 4
    for (int k = strip * 256; k < strip * 256 + 256; ++k)
        acc += inb[k] * w4[k * 128 + col];

    __shared__ float lds[256];
    __shared__ float h2b[128];
    __shared__ float logits[2];
    lds[tid] = acc;
    __syncthreads();
    if (strip == 0) {
        float s = b4[col] + lds[col] + lds[col + 128];
        h2b[col] = s / (1.0f + __expf(-s));   // silu
    }
    __syncthreads();
    if (tid < 2) {
        float a2 = b5[tid];
#pragma unroll 8
        for (int k = 0; k < 128; ++k) a2 += h2b[k] * w5[k * 2 + tid];
        logits[tid] = a2;
    }
    __syncthreads();
    if (tid < H_HEADS)
        out[b * H_HEADS + tid] = (logits[1] > logits[0]) ? 1.0f : 0.0f;
}

extern "C" void kernel_launch(void* const* d_in, const int* in_sizes, int n_in,
                              void* d_out, int out_size, void* d_ws, size_t ws_size,
                              hipStream_t stream) {
    const float* x  = (const float*)d_in[0];
    const int*   cu = (const int*)d_in[1];
    const float* w1 = (const float*)d_in[2];
    const float* b1 = (const float*)d_in[3];
    const float* w2 = (const float*)d_in[4];
    const float* b2 = (const float*)d_in[5];
    const float* w3 = (const float*)d_in[6];
    const float* b3 = (const float*)d_in[7];
    const float* w4 = (const float*)d_in[8];
    const float* b4 = (const float*)d_in[9];
    const float* w5 = (const float*)d_in[10];
    const float* b5 = (const float*)d_in[11];
    float* out = (float*)d_out;

    float* ws   = (float*)d_ws;
    float* sums = ws;                       // 1024
    float* h1   = sums + B_SEG * D_DIM;     // 8192
    float* hm   = h1 + 8192;                // 2048
    float* h2a  = hm + 2048;                // 4096

    // ws is re-poisoned to 0xAA before every timed launch: zero the accumulator.
    (void)hipMemsetAsync(sums, 0, B_SEG * D_DIM * sizeof(float), stream);

    segsum_kernel<<<T_TOK / CHUNK, 256, 0, stream>>>(x, cu, sums);
    // layer1: 128 -> 1024, silu, pooled-mean scale. grid (16,8) = 128 blocks.
    linear2_kernel<128, 1024, 64, true, true>
        <<<dim3(1024 / 64, B_SEG), 256, 0, stream>>>(sums, cu, w1, b1, h1);
    // layer2: 1024 -> 256, no act. grid (8,8) = 64 blocks (COLS=32).
    linear2_kernel<1024, 256, 32, false, false>
        <<<dim3(256 / 32, B_SEG), 256, 0, stream>>>(h1, cu, w2, b2, hm);
    // layer3: 256 -> 512, silu. grid (8,8) = 64 blocks.
    linear2_kernel<256, 512, 64, true, false>
        <<<dim3(512 / 64, B_SEG), 256, 0, stream>>>(hm, cu, w3, b3, h2a);
    // layer4 + layer5 + compare + broadcast: 8 blocks.
    layer4_final_kernel<<<B_SEG, 256, 0, stream>>>(h2a, w4, b4, w5, b5, out);
}

// Round 5
// 255.732 us; speedup vs baseline: 1.3566x; 1.0697x over previous
//
#include <hip/hip_runtime.h>

#define T_TOK   32768
#define B_SEG   8
#define H_HEADS 8
#define D_DIM   128
#define TOK_F   (H_HEADS * D_DIM)   // 1024 floats per token
#define CHUNK   32                  // tokens per block

typedef float floatx4 __attribute__((ext_vector_type(4)));

// ---------------------------------------------------------------------------
// Kernel 1: segment sum over tokens+heads -> sums[B_SEG][D_DIM]
// 1024 blocks x 32 tokens; each thread reads one float4/token (fully
// coalesced). Boundary-free blocks (1017/1024) take a statically unrolled
// branch-free loop (deep vmcnt pipelining); boundary blocks take the
// per-token path. HBM-roofline: 134 MB => ~20 us.
// ---------------------------------------------------------------------------
__global__ __launch_bounds__(256) void segsum_kernel(
        const float* __restrict__ x, const int* __restrict__ cu,
        float* __restrict__ sums) {
    const int tid   = threadIdx.x;
    const int t0    = blockIdx.x * CHUNK;
    const int t_end = t0 + CHUNK;

    int cuv[B_SEG + 1];
#pragma unroll
    for (int i = 0; i <= B_SEG; ++i) cuv[i] = cu[i];

    auto segid = [&](int t) {
        int s = 0;
#pragma unroll
        for (int i = 1; i <= B_SEG; ++i)
            if (cuv[i] <= t) s = i;
        return s;  // searchsorted(cu, t, 'right') - 1
    };

    int cur_seg  = segid(t0);
    int next_cut = cuv[cur_seg + 1];   // guaranteed > t0

    floatx4 acc = (floatx4)0.f;
    __shared__ float smem[TOK_F];
    const floatx4* x4 = (const floatx4*)x + tid;

    auto flush = [&](int seg) {  // block-uniform call sites only
        smem[tid * 4 + 0] = acc.x;
        smem[tid * 4 + 1] = acc.y;
        smem[tid * 4 + 2] = acc.z;
        smem[tid * 4 + 3] = acc.w;
        __syncthreads();
        if (tid < D_DIM) {
            float s = 0.f;
#pragma unroll
            for (int h = 0; h < H_HEADS; ++h) s += smem[h * D_DIM + tid];
            atomicAdd(&sums[seg * D_DIM + tid], s);
        }
        __syncthreads();
        acc = (floatx4)0.f;
    };

    if (next_cut >= t_end) {
#pragma unroll
        for (int i = 0; i < CHUNK; ++i) {
            floatx4 v = __builtin_nontemporal_load(
                x4 + (size_t)(t0 + i) * (TOK_F / 4));
            acc += v;
        }
        flush(cur_seg);
    } else {
        for (int t = t0; t < t_end; ++t) {
            if (t == next_cut) {           // uniform across block
                flush(cur_seg);
                cur_seg  = segid(t);
                next_cut = cuv[cur_seg + 1];
            }
            floatx4 v = x4[(size_t)t * (TOK_F / 4)];
            acc += v;
        }
        flush(cur_seg);
    }
}

// ---------------------------------------------------------------------------
// Kernel 2: entire MLP fused. One block per segment b, 1024 threads.
// Activations live in LDS; each layer is split-K: thread = (strip kk, col
// quad oq), weight reads are coalesced float4 rows, strips reduced via a
// 16 KB LDS scratch. Per-block weight pull = 2.34 MB (w1..w5).
// ---------------------------------------------------------------------------
__device__ __forceinline__ float silu(float v) {
    return v / (1.0f + __expf(-v));
}

__global__ __launch_bounds__(1024) void mlp_fused_kernel(
        const float* __restrict__ sums, const int* __restrict__ cu,
        const float* __restrict__ w1, const float* __restrict__ b1,
        const float* __restrict__ w2, const float* __restrict__ b2,
        const float* __restrict__ w3, const float* __restrict__ b3,
        const float* __restrict__ w4, const float* __restrict__ b4,
        const float* __restrict__ w5, const float* __restrict__ b5,
        float* __restrict__ out) {
    const int b   = blockIdx.x;
    const int tid = threadIdx.x;

    __shared__ floatx4 red[1024];   // 16 KB reduce scratch (reused per layer)
    __shared__ float s_in[128];     // pooled mean
    __shared__ float h1[1024];
    __shared__ float hm[256];
    __shared__ float h2a[512];
    __shared__ float h2b[128];
    __shared__ float logits[2];

    if (tid < 128) {
        const int cnt = cu[b + 1] - cu[b];
        const float scale = 1.0f / (fmaxf((float)cnt, 1.0f) * (float)H_HEADS);
        s_in[tid] = sums[b * 128 + tid] * scale;
    }
    __syncthreads();

    // ---- layer1: 128 -> 1024, silu. 4 strips x 256 col-quads.
    {
        const int oq = tid & 255;
        const int kk = tid >> 8;
        const floatx4* wv = (const floatx4*)w1;   // row = 256 float4
        floatx4 acc = (floatx4)0.f;
#pragma unroll
        for (int k = kk * 32; k < kk * 32 + 32; ++k)
            acc += s_in[k] * wv[k * 256 + oq];
        red[tid] = acc;
        __syncthreads();
        if (kk == 0) {
            floatx4 s = red[oq] + red[oq + 256] + red[oq + 512] + red[oq + 768];
            s += ((const floatx4*)b1)[oq];
            floatx4 r;
            r.x = silu(s.x); r.y = silu(s.y); r.z = silu(s.z); r.w = silu(s.w);
            ((floatx4*)h1)[oq] = r;
        }
        __syncthreads();
    }

    // ---- layer2: 1024 -> 256, no act. 16 strips x 64 col-quads.
    {
        const int oq = tid & 63;
        const int kk = tid >> 6;
        const floatx4* wv = (const floatx4*)w2;   // row = 64 float4
        floatx4 acc = (floatx4)0.f;
#pragma unroll 8
        for (int k = kk * 64; k < kk * 64 + 64; ++k)
            acc += h1[k] * wv[k * 64 + oq];
        red[tid] = acc;
        __syncthreads();
        if (kk == 0) {
            floatx4 s = ((const floatx4*)b2)[oq];
#pragma unroll
            for (int j = 0; j < 16; ++j) s += red[oq + j * 64];
            ((floatx4*)hm)[oq] = s;
        }
        __syncthreads();
    }

    // ---- layer3: 256 -> 512, silu. 8 strips x 128 col-quads.
    {
        const int oq = tid & 127;
        const int kk = tid >> 7;
        const floatx4* wv = (const floatx4*)w3;   // row = 128 float4
        floatx4 acc = (floatx4)0.f;
#pragma unroll
        for (int k = kk * 32; k < kk * 32 + 32; ++k)
            acc += hm[k] * wv[k * 128 + oq];
        red[tid] = acc;
        __syncthreads();
        if (kk == 0) {
            floatx4 s = ((const floatx4*)b3)[oq];
#pragma unroll
            for (int j = 0; j < 8; ++j) s += red[oq + j * 128];
            floatx4 r;
            r.x = silu(s.x); r.y = silu(s.y); r.z = silu(s.z); r.w = silu(s.w);
            ((floatx4*)h2a)[oq] = r;
        }
        __syncthreads();
    }

    // ---- layer4: 512 -> 128, silu. 32 strips x 32 col-quads.
    {
        const int oq = tid & 31;
        const int kk = tid >> 5;
        const floatx4* wv = (const floatx4*)w4;   // row = 32 float4
        floatx4 acc = (floatx4)0.f;
#pragma unroll
        for (int k = kk * 16; k < kk * 16 + 16; ++k)
            acc += h2a[k] * wv[k * 32 + oq];
        red[tid] = acc;
        __syncthreads();
        if (kk == 0) {
            floatx4 s = ((const floatx4*)b4)[oq];
#pragma unroll
            for (int j = 0; j < 32; ++j) s += red[oq + j * 32];
            floatx4 r;
            r.x = silu(s.x); r.y = silu(s.y); r.z = silu(s.z); r.w = silu(s.w);
            ((floatx4*)h2b)[oq] = r;
        }
        __syncthreads();
    }

    // ---- layer5: 128 -> 2, then argmax-compare + broadcast over heads.
    if (tid < 2) {
        float a2 = b5[tid];
#pragma unroll 8
        for (int k = 0; k < 128; ++k) a2 += h2b[k] * w5[k * 2 + tid];
        logits[tid] = a2;
    }
    __syncthreads();
    if (tid < H_HEADS)
        out[b * H_HEADS + tid] = (logits[1] > logits[0]) ? 1.0f : 0.0f;
}

extern "C" void kernel_launch(void* const* d_in, const int* in_sizes, int n_in,
                              void* d_out, int out_size, void* d_ws, size_t ws_size,
                              hipStream_t stream) {
    const float* x  = (const float*)d_in[0];
    const int*   cu = (const int*)d_in[1];
    const float* w1 = (const float*)d_in[2];
    const float* b1 = (const float*)d_in[3];
    const float* w2 = (const float*)d_in[4];
    const float* b2 = (const float*)d_in[5];
    const float* w3 = (const float*)d_in[6];
    const float* b3 = (const float*)d_in[7];
    const float* w4 = (const float*)d_in[8];
    const float* b4 = (const float*)d_in[9];
    const float* w5 = (const float*)d_in[10];
    const float* b5 = (const float*)d_in[11];
    float* out = (float*)d_out;

    float* sums = (float*)d_ws;             // B_SEG * D_DIM floats

    // ws is re-poisoned to 0xAA before every timed launch: zero the accumulator.
    (void)hipMemsetAsync(sums, 0, B_SEG * D_DIM * sizeof(float), stream);

    segsum_kernel<<<T_TOK / CHUNK, 256, 0, stream>>>(x, cu, sums);
    mlp_fused_kernel<<<B_SEG, 1024, 0, stream>>>(
        sums, cu, w1, b1, w2, b2, w3, b3, w4, b4, w5, b5, out);
}